// Round 1
// baseline (797.158 us; speedup 1.0000x reference)
//
#include <hip/hip_runtime.h>
#include <hip/hip_bf16.h>

#define N_PTS 1000000

typedef short bf16x8 __attribute__((ext_vector_type(8)));
typedef float f32x4 __attribute__((ext_vector_type(4)));

__device__ __forceinline__ float bflo(unsigned u) { return __uint_as_float(u << 16); }
__device__ __forceinline__ float bfhi(unsigned u) { return __uint_as_float(u & 0xffff0000u); }

// round-to-nearest-even f32 -> bf16 bits
__device__ __forceinline__ unsigned short f2bf(float f) {
    unsigned u = __float_as_uint(f);
    u += 0x7fffu + ((u >> 16) & 1u);
    return (unsigned short)(u >> 16);
}
__device__ __forceinline__ unsigned pack2(float lo, float hi) {
    return (unsigned)f2bf(lo) | ((unsigned)f2bf(hi) << 16);
}

// ---- pre-pass: [32,H,W] f32 -> [H,W,32] bf16 (channel-last, 64B per texel)
__global__ void transpose_plane(const float* __restrict__ src, unsigned short* __restrict__ dst, int npix) {
    int pix = blockIdx.x * 256 + threadIdx.x;
    float v[32];
#pragma unroll
    for (int c = 0; c < 32; ++c) v[c] = src[(size_t)c * npix + pix];
#pragma unroll
    for (int j = 0; j < 4; ++j) {
        uint4 o;
        o.x = pack2(v[8*j+0], v[8*j+1]);
        o.y = pack2(v[8*j+2], v[8*j+3]);
        o.z = pack2(v[8*j+4], v[8*j+5]);
        o.w = pack2(v[8*j+6], v[8*j+7]);
        *(uint4*)(dst + (size_t)pix * 32 + 8*j) = o;
    }
}

// ---- pre-pass: weights f32 -> bf16 hi (dst[0..n)) + bf16 lo residual (dst[n..2n))
__global__ void f32_to_bf16_split(const float* __restrict__ src, unsigned short* __restrict__ dst, int n) {
    int i = blockIdx.x * 256 + threadIdx.x;
    if (i >= n) return;
    float v = src[i];
    unsigned short h = f2bf(v);
    dst[i] = h;
    float hf = __uint_as_float((unsigned)h << 16);
    dst[n + i] = f2bf(v - hf);
}

// bilinear gather from channel-last bf16 plane; accumulates into feat[32] (f32)
__device__ __forceinline__ void gather_plane(const unsigned short* __restrict__ tp, int R,
                                             float xc, float yc, float feat[32]) {
    float x = (xc + 1.0f) * 0.5f * (float)(R - 1);
    float y = (yc + 1.0f) * 0.5f * (float)(R - 1);
    float fx = floorf(x), fy = floorf(y);
    float wx = x - fx, wy = y - fy;
    int x0 = min(max((int)fx, 0), R - 1);
    int x1 = min(x0 + 1, R - 1);
    int y0 = min(max((int)fy, 0), R - 1);
    int y1 = min(y0 + 1, R - 1);
    float w00 = (1.0f - wx) * (1.0f - wy);
    float w01 = wx * (1.0f - wy);
    float w10 = (1.0f - wx) * wy;
    float w11 = wx * wy;
    const uint4* r00 = (const uint4*)(tp + (size_t)(y0 * R + x0) * 32);
    const uint4* r01 = (const uint4*)(tp + (size_t)(y0 * R + x1) * 32);
    const uint4* r10 = (const uint4*)(tp + (size_t)(y1 * R + x0) * 32);
    const uint4* r11 = (const uint4*)(tp + (size_t)(y1 * R + x1) * 32);
#pragma unroll
    for (int j = 0; j < 4; ++j) {
        uint4 a = r00[j], b = r01[j], c = r10[j], d = r11[j];
        const unsigned* pa = &a.x; const unsigned* pb = &b.x;
        const unsigned* pc = &c.x; const unsigned* pd = &d.x;
#pragma unroll
        for (int t = 0; t < 4; ++t) {
            feat[8*j+2*t]   += w00*bflo(pa[t]) + w01*bflo(pb[t]) + w10*bflo(pc[t]) + w11*bflo(pd[t]);
            feat[8*j+2*t+1] += w00*bfhi(pa[t]) + w01*bfhi(pb[t]) + w10*bfhi(pc[t]) + w11*bfhi(pd[t]);
        }
    }
}

__device__ __forceinline__ void write_feat(unsigned short* Lrow, const float feat[32]) {
#pragma unroll
    for (int j = 0; j < 4; ++j) {
        uint4 v;
        v.x = pack2(feat[8*j+0], feat[8*j+1]);
        v.y = pack2(feat[8*j+2], feat[8*j+3]);
        v.z = pack2(feat[8*j+4], feat[8*j+5]);
        v.w = pack2(feat[8*j+6], feat[8*j+7]);
        *(uint4*)(Lrow + 8*j) = v;
    }
}

// wave-local LDS fence (waves are independent; no __syncthreads anywhere)
#define LDS_FENCE() asm volatile("s_waitcnt lgkmcnt(0)" ::: "memory")

// one wave, 64 points: [64,K] (LDS, stride SA) x [K,16*NT] (global bf16 hi+lo) -> relu -> LDS (stride SB)
// A-frag: lane holds A[row=c0][k=8*q0+j+32*ks]; B-frag: W[n=16nt+c0][k] (8 contiguous k per lane)
// C/D: col=c0, row=4*q0+reg  (m89-verified)
template <int KT, int NT>
__device__ __forceinline__ void gemm_relu_store(const unsigned short* L, int SA,
                                                unsigned short* Lout, int SB, int colOff,
                                                const unsigned short* __restrict__ Wg, int K,
                                                const float* __restrict__ bias,
                                                int c0, int q0) {
    constexpr int WSZ = NT * 16 * 0 + 0;  // placeholder to keep template simple
    const int wsz = NT * 16 * K;          // elems in hi block; lo follows
    bf16x8 A[4][KT];
#pragma unroll
    for (int mt = 0; mt < 4; ++mt)
#pragma unroll
        for (int ks = 0; ks < KT; ++ks)
            A[mt][ks] = *(const bf16x8*)(L + (16*mt + c0) * SA + 8*q0 + 32*ks);
#pragma unroll
    for (int nt = 0; nt < NT; ++nt) {
        bf16x8 Bh[KT], Bl[KT];
#pragma unroll
        for (int ks = 0; ks < KT; ++ks) {
            Bh[ks] = *(const bf16x8*)(Wg + (size_t)(16*nt + c0) * K + 8*q0 + 32*ks);
            Bl[ks] = *(const bf16x8*)(Wg + wsz + (size_t)(16*nt + c0) * K + 8*q0 + 32*ks);
        }
        float bv = bias[16*nt + c0];
#pragma unroll
        for (int mt = 0; mt < 4; ++mt) {
            f32x4 acc = {0.f, 0.f, 0.f, 0.f};
#pragma unroll
            for (int ks = 0; ks < KT; ++ks) {
                acc = __builtin_amdgcn_mfma_f32_16x16x32_bf16(A[mt][ks], Bh[ks], acc, 0, 0, 0);
                acc = __builtin_amdgcn_mfma_f32_16x16x32_bf16(A[mt][ks], Bl[ks], acc, 0, 0, 0);
            }
#pragma unroll
            for (int i = 0; i < 4; ++i) {
                float v = fmaxf(acc[i] + bv, 0.0f);
                Lout[(16*mt + 4*q0 + i) * SB + colOff + 16*nt + c0] = f2bf(v);
            }
        }
    }
    (void)WSZ;
}

__device__ __forceinline__ float qreduce16(float v) {
    v += __shfl_xor(v, 1, 64);
    v += __shfl_xor(v, 2, 64);
    v += __shfl_xor(v, 4, 64);
    v += __shfl_xor(v, 8, 64);
    return v;
}

__global__ __launch_bounds__(128) void decoder_main(
    const float* __restrict__ p,
    const unsigned short* __restrict__ ws,
    const float* __restrict__ lin0_b, const float* __restrict__ lin1_b,
    const float* __restrict__ comb0_b, const float* __restrict__ comb1_b,
    const float* __restrict__ out_w, const float* __restrict__ out_b,
    const float* __restrict__ clin0_b, const float* __restrict__ clin1_b,
    const float* __restrict__ cout_w, const float* __restrict__ cout_b,
    float* __restrict__ out) {
    __shared__ unsigned short lds[2][8704];   // per-wave slice, max stage 64 rows x stride 136
    const int tid = threadIdx.x;
    const int wave = tid >> 6, lane = tid & 63;
    const int c0 = lane & 15, q0 = lane >> 4;
    const int pbase = blockIdx.x * 128 + wave * 64;
    if (pbase >= N_PTS) return;
    const int pt = pbase + lane;
    unsigned short* L = lds[wave];

    const float px = p[3*(size_t)pt], py = p[3*(size_t)pt+1], pz = p[3*(size_t)pt+2];

    const unsigned short* PXY_C = ws;
    const unsigned short* PXZ_C = ws + 524288;
    const unsigned short* PYZ_C = ws + 1048576;
    const unsigned short* PXY_F = ws + 1572864;
    const unsigned short* PXZ_F = ws + 9961472;
    const unsigned short* PYZ_F = ws + 18350080;
    const unsigned short* PCXY  = ws + 26738688;
    const unsigned short* PCXZ  = ws + 28835840;
    const unsigned short* PCYZ  = ws + 30932992;
    const unsigned short* WB  = ws + 33030144;   // weights: hi block then lo block per matrix
    const unsigned short* W0  = WB;              // [64][32]   hi@0   lo@2048
    const unsigned short* W1  = WB + 4096;       // [64][64]
    const unsigned short* WC0 = WB + 12288;      // [128][96]
    const unsigned short* WC1 = WB + 36864;      // [128][128]
    const unsigned short* WL0 = WB + 69632;      // [64][32]
    const unsigned short* WL1 = WB + 73728;      // [64][64]

    // ---- feat_c -> LDS stride 40
    {
        float feat[32];
#pragma unroll
        for (int c2 = 0; c2 < 32; ++c2) feat[c2] = 0.f;
        gather_plane(PXY_C, 128, px, py, feat);
        gather_plane(PXZ_C, 128, px, pz, feat);
        gather_plane(PYZ_C, 128, py, pz, feat);
        write_feat(L + lane * 40, feat);
    }
    LDS_FENCE();
    gemm_relu_store<1, 4>(L, 40, L, 72, 0, W0, 32, lin0_b, c0, q0);   // -> h0 [64][64] stride 72
    LDS_FENCE();
    gemm_relu_store<2, 4>(L, 72, L, 104, 0, W1, 64, lin1_b, c0, q0);  // -> h1 cols 0..63 stride 104
    LDS_FENCE();
    // ---- feat_f -> cols 64..95 (stride 104)
    {
        float feat[32];
#pragma unroll
        for (int c2 = 0; c2 < 32; ++c2) feat[c2] = 0.f;
        gather_plane(PXY_F, 512, px, py, feat);
        gather_plane(PXZ_F, 512, px, pz, feat);
        gather_plane(PYZ_F, 512, py, pz, feat);
        write_feat(L + lane * 104 + 64, feat);
    }
    LDS_FENCE();
    gemm_relu_store<3, 8>(L, 104, L, 136, 0, WC0, 96, comb0_b, c0, q0); // -> h2 [64][128] stride 136
    LDS_FENCE();

    // ---- comb1 (K=128) with fused sdf fold: sdf = sum_col out_w[col]*relu(acc+b)
    float part[16];
#pragma unroll
    for (int r = 0; r < 16; ++r) part[r] = 0.f;
    {
        bf16x8 A[4][4];
#pragma unroll
        for (int mt = 0; mt < 4; ++mt)
#pragma unroll
            for (int ks = 0; ks < 4; ++ks)
                A[mt][ks] = *(const bf16x8*)(L + (16*mt + c0) * 136 + 8*q0 + 32*ks);
#pragma unroll
        for (int nt = 0; nt < 8; ++nt) {
            bf16x8 Bh[4], Bl[4];
#pragma unroll
            for (int ks = 0; ks < 4; ++ks) {
                Bh[ks] = *(const bf16x8*)(WC1 + (size_t)(16*nt + c0) * 128 + 8*q0 + 32*ks);
                Bl[ks] = *(const bf16x8*)(WC1 + 16384 + (size_t)(16*nt + c0) * 128 + 8*q0 + 32*ks);
            }
            float bv = comb1_b[16*nt + c0];
            float wo = out_w[16*nt + c0];
#pragma unroll
            for (int mt = 0; mt < 4; ++mt) {
                f32x4 acc = {0.f,0.f,0.f,0.f};
#pragma unroll
                for (int ks = 0; ks < 4; ++ks) {
                    acc = __builtin_amdgcn_mfma_f32_16x16x32_bf16(A[mt][ks], Bh[ks], acc, 0, 0, 0);
                    acc = __builtin_amdgcn_mfma_f32_16x16x32_bf16(A[mt][ks], Bl[ks], acc, 0, 0, 0);
                }
#pragma unroll
                for (int i = 0; i < 4; ++i)
                    part[4*mt + i] += wo * fmaxf(acc[i] + bv, 0.0f);
            }
        }
    }

    // ---- color path: cf -> clin0 -> clin1 (+ fused cout fold)
    {
        float feat[32];
#pragma unroll
        for (int c2 = 0; c2 < 32; ++c2) feat[c2] = 0.f;
        gather_plane(PCXY, 256, px, py, feat);
        gather_plane(PCXZ, 256, px, pz, feat);
        gather_plane(PCYZ, 256, py, pz, feat);
        write_feat(L + lane * 40, feat);
    }
    LDS_FENCE();
    gemm_relu_store<1, 4>(L, 40, L, 72, 0, WL0, 32, clin0_b, c0, q0);
    LDS_FENCE();

    float partc0[16], partc1[16], partc2[16];
#pragma unroll
    for (int r = 0; r < 16; ++r) { partc0[r]=0.f; partc1[r]=0.f; partc2[r]=0.f; }
    {
        bf16x8 A[4][2];
#pragma unroll
        for (int mt = 0; mt < 4; ++mt)
#pragma unroll
            for (int ks = 0; ks < 2; ++ks)
                A[mt][ks] = *(const bf16x8*)(L + (16*mt + c0) * 72 + 8*q0 + 32*ks);
#pragma unroll
        for (int nt = 0; nt < 4; ++nt) {
            bf16x8 Bh[2], Bl[2];
#pragma unroll
            for (int ks = 0; ks < 2; ++ks) {
                Bh[ks] = *(const bf16x8*)(WL1 + (size_t)(16*nt + c0) * 64 + 8*q0 + 32*ks);
                Bl[ks] = *(const bf16x8*)(WL1 + 4096 + (size_t)(16*nt + c0) * 64 + 8*q0 + 32*ks);
            }
            float bv = clin1_b[16*nt + c0];
            float cw0 = cout_w[16*nt + c0];
            float cw1 = cout_w[64 + 16*nt + c0];
            float cw2 = cout_w[128 + 16*nt + c0];
#pragma unroll
            for (int mt = 0; mt < 4; ++mt) {
                f32x4 acc = {0.f,0.f,0.f,0.f};
#pragma unroll
                for (int ks = 0; ks < 2; ++ks) {
                    acc = __builtin_amdgcn_mfma_f32_16x16x32_bf16(A[mt][ks], Bh[ks], acc, 0, 0, 0);
                    acc = __builtin_amdgcn_mfma_f32_16x16x32_bf16(A[mt][ks], Bl[ks], acc, 0, 0, 0);
                }
#pragma unroll
                for (int i = 0; i < 4; ++i) {
                    float hv = fmaxf(acc[i] + bv, 0.0f);
                    partc0[4*mt+i] += cw0 * hv;
                    partc1[4*mt+i] += cw1 * hv;
                    partc2[4*mt+i] += cw2 * hv;
                }
            }
        }
    }

    // reduce partials across the 16 lanes of each quadrant (cols)
#pragma unroll
    for (int r = 0; r < 16; ++r) {
        part[r]   = qreduce16(part[r]);
        partc0[r] = qreduce16(partc0[r]);
        partc1[r] = qreduce16(partc1[r]);
        partc2[r] = qreduce16(partc2[r]);
    }

    if (c0 == 0) {
        const float ob = out_b[0];
        const float cb0 = cout_b[0], cb1 = cout_b[1], cb2 = cout_b[2];
#pragma unroll
        for (int mt = 0; mt < 4; ++mt)
#pragma unroll
            for (int i = 0; i < 4; ++i) {
                int r = 4*mt + i;
                int row = 16*mt + 4*q0 + i;
                float4 o;
                o.x = 1.0f / (1.0f + __expf(-(partc0[r] + cb0)));
                o.y = 1.0f / (1.0f + __expf(-(partc1[r] + cb1)));
                o.z = 1.0f / (1.0f + __expf(-(partc2[r] + cb2)));
                o.w = part[r] + ob;
                *(float4*)(out + (size_t)(pbase + row) * 4) = o;
            }
    }
}

extern "C" void kernel_launch(void* const* d_in, const int* in_sizes, int n_in,
                              void* d_out, int out_size, void* d_ws, size_t ws_size,
                              hipStream_t stream) {
    // ws layout (bf16 elems): 9 channel-last planes (33,030,144) + split weights (81,920)
    if (ws_size < 66224128u) return;  // need ~63.2 MiB scratch
    unsigned short* ws = (unsigned short*)d_ws;

    static const int    npix[9] = {16384,16384,16384,262144,262144,262144,65536,65536,65536};
    static const size_t poff[9] = {0,524288,1048576,1572864,9961472,18350080,26738688,28835840,30932992};
    for (int i = 0; i < 9; ++i)
        transpose_plane<<<npix[i]/256, 256, 0, stream>>>((const float*)d_in[1+i], ws + poff[i], npix[i]);

    static const int    widx[6] = {10,12,14,16,20,22};           // lin0_w,lin1_w,comb0_w,comb1_w,clin0_w,clin1_w
    static const int    wn[6]   = {2048,4096,12288,16384,2048,4096};
    static const size_t woff[6] = {0,4096,12288,36864,69632,73728};
    unsigned short* wb = ws + 33030144;
    for (int i = 0; i < 6; ++i)
        f32_to_bf16_split<<<wn[i]/256, 256, 0, stream>>>((const float*)d_in[widx[i]], wb + woff[i], wn[i]);

    decoder_main<<<(N_PTS + 127)/128, 128, 0, stream>>>(
        (const float*)d_in[0], ws,
        (const float*)d_in[11], (const float*)d_in[13],
        (const float*)d_in[15], (const float*)d_in[17],
        (const float*)d_in[18], (const float*)d_in[19],
        (const float*)d_in[21], (const float*)d_in[23],
        (const float*)d_in[24], (const float*)d_in[25],
        (float*)d_out);
}

// Round 2
// 574.906 us; speedup vs baseline: 1.3866x; 1.3866x over previous
//
#include <hip/hip_runtime.h>
#include <hip/hip_bf16.h>

#define N_PTS 1000000

typedef short bf16x8 __attribute__((ext_vector_type(8)));
typedef float f32x4 __attribute__((ext_vector_type(4)));

__device__ __forceinline__ float bflo(unsigned u) { return __uint_as_float(u << 16); }
__device__ __forceinline__ float bfhi(unsigned u) { return __uint_as_float(u & 0xffff0000u); }

__device__ __forceinline__ unsigned short f2bf(float f) {
    unsigned u = __float_as_uint(f);
    u += 0x7fffu + ((u >> 16) & 1u);
    return (unsigned short)(u >> 16);
}
__device__ __forceinline__ unsigned pack2(float lo, float hi) {
    return (unsigned)f2bf(lo) | ((unsigned)f2bf(hi) << 16);
}

// ---- pre-pass: [32,H,W] f32 -> [H,W,32] bf16 (channel-last, 64B per texel)
__global__ void transpose_plane(const float* __restrict__ src, unsigned short* __restrict__ dst, int npix) {
    int pix = blockIdx.x * 256 + threadIdx.x;
    float v[32];
#pragma unroll
    for (int c = 0; c < 32; ++c) v[c] = src[(size_t)c * npix + pix];
#pragma unroll
    for (int j = 0; j < 4; ++j) {
        uint4 o;
        o.x = pack2(v[8*j+0], v[8*j+1]);
        o.y = pack2(v[8*j+2], v[8*j+3]);
        o.z = pack2(v[8*j+4], v[8*j+5]);
        o.w = pack2(v[8*j+6], v[8*j+7]);
        *(uint4*)(dst + (size_t)pix * 32 + 8*j) = o;
    }
}

// ---- pre-pass: weights f32 -> bf16 (hi only; lo-split dropped, absmax margin 3.7x)
__global__ void f32_to_bf16_k(const float* __restrict__ src, unsigned short* __restrict__ dst, int n) {
    int i = blockIdx.x * 256 + threadIdx.x;
    if (i < n) dst[i] = f2bf(src[i]);
}

#define LDS_FENCE() asm volatile("s_waitcnt lgkmcnt(0)" ::: "memory")

// Coalesced 3-plane gather group. Lane = (sub=lane>>2 -> point, chunk=lane&3 -> 8-ch slice).
// Per round: 16 points; each load inst covers 16 lines (4 lanes share a 64B texel line).
// Result ds_written as bf16 [64 pts][32 ch], row stride 64 B, XOR swizzle (row&3)<<4.
__device__ __forceinline__ void gather_group(
    const unsigned short* __restrict__ P0, const unsigned short* __restrict__ P1,
    const unsigned short* __restrict__ P2, int R,
    const float* __restrict__ p, int pbase, int lane, unsigned short* dst) {
    const int sub = lane >> 2, chunk = lane & 3;
    const float Rs = 0.5f * (float)(R - 1);
#pragma unroll
    for (int r = 0; r < 4; ++r) {
        const int row = r * 16 + sub;
        const float* pp = p + 3 * (size_t)(pbase + row);
        const float pa = pp[0], pb = pp[1], pc = pp[2];
        float acc[8];
#pragma unroll
        for (int c = 0; c < 8; ++c) acc[c] = 0.f;
        const unsigned short* tp[3] = {P0, P1, P2};
        const float cA[3] = {pa, pa, pb};
        const float cB[3] = {pb, pc, pc};
#pragma unroll
        for (int pl = 0; pl < 3; ++pl) {
            float x = (cA[pl] + 1.0f) * Rs;
            float y = (cB[pl] + 1.0f) * Rs;
            float fx = floorf(x), fy = floorf(y);
            float wx = x - fx, wy = y - fy;
            int x0 = min(max((int)fx, 0), R - 1);
            int x1 = min(x0 + 1, R - 1);
            int y0 = min(max((int)fy, 0), R - 1);
            int y1 = min(y0 + 1, R - 1);
            float w00 = (1.0f - wx) * (1.0f - wy);
            float w01 = wx * (1.0f - wy);
            float w10 = (1.0f - wx) * wy;
            float w11 = wx * wy;
            const unsigned short* b = tp[pl];
            uint4 v00 = *(const uint4*)(b + (size_t)(y0 * R + x0) * 32 + chunk * 8);
            uint4 v01 = *(const uint4*)(b + (size_t)(y0 * R + x1) * 32 + chunk * 8);
            uint4 v10 = *(const uint4*)(b + (size_t)(y1 * R + x0) * 32 + chunk * 8);
            uint4 v11 = *(const uint4*)(b + (size_t)(y1 * R + x1) * 32 + chunk * 8);
            const unsigned* a0 = &v00.x; const unsigned* a1 = &v01.x;
            const unsigned* a2 = &v10.x; const unsigned* a3 = &v11.x;
#pragma unroll
            for (int t = 0; t < 4; ++t) {
                acc[2*t]   += w00*bflo(a0[t]) + w01*bflo(a1[t]) + w10*bflo(a2[t]) + w11*bflo(a3[t]);
                acc[2*t+1] += w00*bfhi(a0[t]) + w01*bfhi(a1[t]) + w10*bfhi(a2[t]) + w11*bfhi(a3[t]);
            }
        }
        uint4 o;
        o.x = pack2(acc[0], acc[1]);
        o.y = pack2(acc[2], acc[3]);
        o.z = pack2(acc[4], acc[5]);
        o.w = pack2(acc[6], acc[7]);
        *(uint4*)((char*)dst + row * 64 + ((chunk * 16) ^ ((row & 3) << 4))) = o;
    }
}

// [64,K] (LDS, swizzled) x [K,16*NT] (W bf16, row-major [N][K]) -> relu -> LDS (swizzled b16 scalar)
template <int KT, int NT, int SWA, int SWO>
__device__ __forceinline__ void gemm_relu_store(
    const unsigned short* A0, int RSA, unsigned short* O, int RSO,
    const unsigned short* __restrict__ Wg, int K,
    const float* __restrict__ bias, int c0, int q0) {
    bf16x8 A[4][KT];
#pragma unroll
    for (int mt = 0; mt < 4; ++mt) {
        const int row = 16 * mt + c0;
#pragma unroll
        for (int ks = 0; ks < KT; ++ks)
            A[mt][ks] = *(const bf16x8*)((const char*)A0 + row * RSA + ((16*q0 + 64*ks) ^ ((row & SWA) << 4)));
    }
#pragma unroll
    for (int nt = 0; nt < NT; ++nt) {
        bf16x8 B[KT];
#pragma unroll
        for (int ks = 0; ks < KT; ++ks)
            B[ks] = *(const bf16x8*)(Wg + (size_t)(16*nt + c0) * K + 8*q0 + 32*ks);
        const float bv = bias[16*nt + c0];
#pragma unroll
        for (int mt = 0; mt < 4; ++mt) {
            f32x4 acc = {0.f, 0.f, 0.f, 0.f};
#pragma unroll
            for (int ks = 0; ks < KT; ++ks)
                acc = __builtin_amdgcn_mfma_f32_16x16x32_bf16(A[mt][ks], B[ks], acc, 0, 0, 0);
#pragma unroll
            for (int i = 0; i < 4; ++i) {
                const float v = fmaxf(acc[i] + bv, 0.0f);
                const int row = 16*mt + 4*q0 + i;
                *(unsigned short*)((char*)O + row * RSO + ((2*(16*nt + c0)) ^ ((row & SWO) << 4))) = f2bf(v);
            }
        }
    }
}

__global__ __launch_bounds__(128) void decoder_main(
    const float* __restrict__ p,
    const unsigned short* __restrict__ ws,
    const float* __restrict__ lin0_b, const float* __restrict__ lin1_b,
    const float* __restrict__ comb0_b, const float* __restrict__ comb1_b,
    const float* __restrict__ out_w, const float* __restrict__ out_b,
    const float* __restrict__ clin0_b, const float* __restrict__ clin1_b,
    const float* __restrict__ cout_w, const float* __restrict__ cout_b,
    float* __restrict__ out) {
    __shared__ unsigned short lds[2][8192];   // 16 KB per wave, tightly packed
    const int tid = threadIdx.x;
    const int wave = tid >> 6, lane = tid & 63;
    const int c0 = lane & 15, q0 = lane >> 4;
    const int pbase = blockIdx.x * 128 + wave * 64;
    if (pbase >= N_PTS) return;
    unsigned short* L = lds[wave];

    const unsigned short* PXY_C = ws;
    const unsigned short* PXZ_C = ws + 524288;
    const unsigned short* PYZ_C = ws + 1048576;
    const unsigned short* PXY_F = ws + 1572864;
    const unsigned short* PXZ_F = ws + 9961472;
    const unsigned short* PYZ_F = ws + 18350080;
    const unsigned short* PCXY  = ws + 26738688;
    const unsigned short* PCXZ  = ws + 28835840;
    const unsigned short* PCYZ  = ws + 30932992;
    const unsigned short* WB  = ws + 33030144;   // bf16 weights (hi only)
    const unsigned short* W0  = WB;              // [64][32]
    const unsigned short* W1  = WB + 2048;       // [64][64]
    const unsigned short* WC0 = WB + 6144;       // [128][96]
    const unsigned short* WC1 = WB + 18432;      // [128][128]
    const unsigned short* WL0 = WB + 34816;      // [64][32]
    const unsigned short* WL1 = WB + 36864;      // [64][64]

    // LDS map (bytes, per wave): featc@0 (4K), h0@4096 (8K), h1@0 (8K),
    // featf@12288 (4K), h2@0 (16K), featc2@0, h0c@4096, reduce@0 (16K).
    unsigned short* FEATC = L;
    unsigned short* H0    = L + 2048;
    unsigned short* H1    = L;
    unsigned short* FEATF = L + 6144;  // byte 12288
    unsigned short* H2    = L;

    // gathers: coarse now, fine issued early (latency hides under lin0/lin1)
    gather_group(PXY_C, PXZ_C, PYZ_C, 128, p, pbase, lane, FEATC);
    gather_group(PXY_F, PXZ_F, PYZ_F, 512, p, pbase, lane, FEATF);
    LDS_FENCE();
    gemm_relu_store<1, 4, 3, 7>(FEATC, 64, H0, 128, W0, 32, lin0_b, c0, q0);
    LDS_FENCE();
    gemm_relu_store<2, 4, 7, 7>(H0, 128, H1, 128, W1, 64, lin1_b, c0, q0);
    LDS_FENCE();

    // comb0: A = [h1 (ks 0,1) | featf (ks 2)] -> h2 [64][128]
    {
        bf16x8 A[4][3];
#pragma unroll
        for (int mt = 0; mt < 4; ++mt) {
            const int row = 16*mt + c0;
#pragma unroll
            for (int ks = 0; ks < 2; ++ks)
                A[mt][ks] = *(const bf16x8*)((const char*)H1 + row * 128 + ((16*q0 + 64*ks) ^ ((row & 7) << 4)));
            A[mt][2] = *(const bf16x8*)((const char*)FEATF + row * 64 + ((16*q0) ^ ((row & 3) << 4)));
        }
#pragma unroll
        for (int nt = 0; nt < 8; ++nt) {
            bf16x8 B[3];
#pragma unroll
            for (int ks = 0; ks < 3; ++ks)
                B[ks] = *(const bf16x8*)(WC0 + (size_t)(16*nt + c0) * 96 + 8*q0 + 32*ks);
            const float bv = comb0_b[16*nt + c0];
#pragma unroll
            for (int mt = 0; mt < 4; ++mt) {
                f32x4 acc = {0.f,0.f,0.f,0.f};
#pragma unroll
                for (int ks = 0; ks < 3; ++ks)
                    acc = __builtin_amdgcn_mfma_f32_16x16x32_bf16(A[mt][ks], B[ks], acc, 0, 0, 0);
#pragma unroll
                for (int i = 0; i < 4; ++i) {
                    const float v = fmaxf(acc[i] + bv, 0.0f);
                    const int row = 16*mt + 4*q0 + i;
                    *(unsigned short*)((char*)H2 + row * 256 + ((2*(16*nt + c0)) ^ ((row & 7) << 4))) = f2bf(v);
                }
            }
        }
    }
    LDS_FENCE();

    // comb1 (K=128) + fused sdf fold; color gather overlapped under the MFMAs
    float part[16];
#pragma unroll
    for (int r = 0; r < 16; ++r) part[r] = 0.f;
    {
        bf16x8 A[4][4];
#pragma unroll
        for (int mt = 0; mt < 4; ++mt) {
            const int row = 16*mt + c0;
#pragma unroll
            for (int ks = 0; ks < 4; ++ks)
                A[mt][ks] = *(const bf16x8*)((const char*)H2 + row * 256 + ((16*q0 + 64*ks) ^ ((row & 7) << 4)));
        }
        // color gather writes featc2 over bytes 0..4K (h2 fully in regs; per-wave DS FIFO keeps order)
        gather_group(PCXY, PCXZ, PCYZ, 256, p, pbase, lane, FEATC);
#pragma unroll
        for (int nt = 0; nt < 8; ++nt) {
            bf16x8 B[4];
#pragma unroll
            for (int ks = 0; ks < 4; ++ks)
                B[ks] = *(const bf16x8*)(WC1 + (size_t)(16*nt + c0) * 128 + 8*q0 + 32*ks);
            const float bv = comb1_b[16*nt + c0];
            const float wo = out_w[16*nt + c0];
#pragma unroll
            for (int mt = 0; mt < 4; ++mt) {
                f32x4 acc = {0.f,0.f,0.f,0.f};
#pragma unroll
                for (int ks = 0; ks < 4; ++ks)
                    acc = __builtin_amdgcn_mfma_f32_16x16x32_bf16(A[mt][ks], B[ks], acc, 0, 0, 0);
#pragma unroll
                for (int i = 0; i < 4; ++i)
                    part[4*mt + i] += wo * fmaxf(acc[i] + bv, 0.0f);
            }
        }
    }
    LDS_FENCE();
    gemm_relu_store<1, 4, 3, 7>(FEATC, 64, H0, 128, WL0, 32, clin0_b, c0, q0);
    LDS_FENCE();

    // clin1 + fused cout fold
    float partc0[16], partc1[16], partc2[16];
#pragma unroll
    for (int r = 0; r < 16; ++r) { partc0[r]=0.f; partc1[r]=0.f; partc2[r]=0.f; }
    {
        bf16x8 A[4][2];
#pragma unroll
        for (int mt = 0; mt < 4; ++mt) {
            const int row = 16*mt + c0;
#pragma unroll
            for (int ks = 0; ks < 2; ++ks)
                A[mt][ks] = *(const bf16x8*)((const char*)H0 + row * 128 + ((16*q0 + 64*ks) ^ ((row & 7) << 4)));
        }
#pragma unroll
        for (int nt = 0; nt < 4; ++nt) {
            bf16x8 B[2];
#pragma unroll
            for (int ks = 0; ks < 2; ++ks)
                B[ks] = *(const bf16x8*)(WL1 + (size_t)(16*nt + c0) * 64 + 8*q0 + 32*ks);
            const float bv = clin1_b[16*nt + c0];
            const float cw0 = cout_w[16*nt + c0];
            const float cw1 = cout_w[64 + 16*nt + c0];
            const float cw2 = cout_w[128 + 16*nt + c0];
#pragma unroll
            for (int mt = 0; mt < 4; ++mt) {
                f32x4 acc = {0.f,0.f,0.f,0.f};
#pragma unroll
                for (int ks = 0; ks < 2; ++ks)
                    acc = __builtin_amdgcn_mfma_f32_16x16x32_bf16(A[mt][ks], B[ks], acc, 0, 0, 0);
#pragma unroll
                for (int i = 0; i < 4; ++i) {
                    const float hv = fmaxf(acc[i] + bv, 0.0f);
                    partc0[4*mt+i] += cw0 * hv;
                    partc1[4*mt+i] += cw1 * hv;
                    partc2[4*mt+i] += cw2 * hv;
                }
            }
        }
    }

    // LDS-transpose reduction over the 16 c0 lanes; coalesced float4 store from all lanes
    {
        char* RB = (char*)L;
#pragma unroll
        for (int mt = 0; mt < 4; ++mt)
#pragma unroll
            for (int i = 0; i < 4; ++i) {
                const int r = 4*mt + i;
                const int row = 16*mt + 4*q0 + i;
                float4 v; v.x = partc0[r]; v.y = partc1[r]; v.z = partc2[r]; v.w = part[r];
                *(float4*)(RB + row * 256 + ((c0 * 16) ^ ((row & 7) << 4))) = v;
            }
    }
    LDS_FENCE();
    {
        float4 s; s.x = 0.f; s.y = 0.f; s.z = 0.f; s.w = 0.f;
#pragma unroll
        for (int c = 0; c < 16; ++c) {
            float4 v = *(const float4*)((const char*)L + lane * 256 + ((c * 16) ^ ((lane & 7) << 4)));
            s.x += v.x; s.y += v.y; s.z += v.z; s.w += v.w;
        }
        float4 o;
        o.x = 1.0f / (1.0f + __expf(-(s.x + cout_b[0])));
        o.y = 1.0f / (1.0f + __expf(-(s.y + cout_b[1])));
        o.z = 1.0f / (1.0f + __expf(-(s.z + cout_b[2])));
        o.w = s.w + out_b[0];
        *(float4*)(out + 4 * (size_t)(pbase + lane)) = o;
    }
}

extern "C" void kernel_launch(void* const* d_in, const int* in_sizes, int n_in,
                              void* d_out, int out_size, void* d_ws, size_t ws_size,
                              hipStream_t stream) {
    // ws (bf16 elems): 9 channel-last planes (33,030,144) + bf16 weights (40,960)
    if (ws_size < 66142208u) return;  // ~63.1 MiB
    unsigned short* ws = (unsigned short*)d_ws;

    static const int    npix[9] = {16384,16384,16384,262144,262144,262144,65536,65536,65536};
    static const size_t poff[9] = {0,524288,1048576,1572864,9961472,18350080,26738688,28835840,30932992};
    for (int i = 0; i < 9; ++i)
        transpose_plane<<<npix[i]/256, 256, 0, stream>>>((const float*)d_in[1+i], ws + poff[i], npix[i]);

    static const int    widx[6] = {10,12,14,16,20,22};   // lin0_w,lin1_w,comb0_w,comb1_w,clin0_w,clin1_w
    static const int    wn[6]   = {2048,4096,12288,16384,2048,4096};
    static const size_t woff[6] = {0,2048,6144,18432,34816,36864};
    unsigned short* wb = ws + 33030144;
    for (int i = 0; i < 6; ++i)
        f32_to_bf16_k<<<(wn[i]+255)/256, 256, 0, stream>>>((const float*)d_in[widx[i]], wb + woff[i], wn[i]);

    decoder_main<<<(N_PTS + 127)/128, 128, 0, stream>>>(
        (const float*)d_in[0], ws,
        (const float*)d_in[11], (const float*)d_in[13],
        (const float*)d_in[15], (const float*)d_in[17],
        (const float*)d_in[18], (const float*)d_in[19],
        (const float*)d_in[21], (const float*)d_in[23],
        (const float*)d_in[24], (const float*)d_in[25],
        (float*)d_out);
}